// Round 3
// baseline (214.265 us; speedup 1.0000x reference)
//
#include <hip/hip_runtime.h>
#include <hip/hip_bf16.h>
#include <hip/hip_cooperative_groups.h>

namespace cg = cooperative_groups;

#define BB 4
#define TT 2048
#define DD 128
#define CHK 64
#define NCHK 32            // TT/CHK
#define NCHKS (BB*NCHK)    // 128 chunks total
#define NBLK 256

typedef __attribute__((ext_vector_type(8))) short  bf16x8;
typedef __attribute__((ext_vector_type(4))) float  f32x4;

#define MFMA(a,b,c) __builtin_amdgcn_mfma_f32_16x16x32_bf16(a, b, c, 0, 0, 0)

__device__ __forceinline__ short f2b(float f) {
    union { float f; unsigned u; } x; x.f = f;
    unsigned r = x.u + 0x7fffu + ((x.u >> 16) & 1u);   // RNE
    return (short)(r >> 16);
}
__device__ __forceinline__ float b2f(short s) {
    union { unsigned u; float f; } x; x.u = ((unsigned)(unsigned short)s) << 16;
    return x.f;
}
__device__ __forceinline__ bf16x8 cvt8(const float* p) {
    float4 a = *(const float4*)p, b = *(const float4*)(p + 4);
    bf16x8 r;
    r[0]=f2b(a.x); r[1]=f2b(a.y); r[2]=f2b(a.z); r[3]=f2b(a.w);
    r[4]=f2b(b.x); r[5]=f2b(b.y); r[6]=f2b(b.z); r[7]=f2b(b.w);
    return r;
}

// ---------------------------------------------------------------------------
// One cooperative kernel, 256 blocks x 256 threads.
//   phase0: convert W->bf16 (1/256 per block); build vT half; prefetch A-frags
//   phaseA: chunk c = bid>>1, e-half h = bid&1: phi(k) (full), z_c (h==0),
//           S_half = Kf^T V_half -> SsT_g fp32 [c][e][d]; vT half -> global
//   phaseB: exclusive chunk-prefix scan (2 (b,e)-tasks per block) -> SpT bf16
//   phaseC: phi(q),phi(k) full; P=QK^T masked; den; out half = P@V + Q@Sp
// ---------------------------------------------------------------------------
__global__ __launch_bounds__(256, 1) void fused(const float* __restrict__ q,
                                                const float* __restrict__ kin,
                                                const float* __restrict__ vin,
                                                const float* __restrict__ W,
                                                const float* __restrict__ bias,
                                                short* __restrict__ Wb,
                                                float* __restrict__ SsT_g,
                                                float* __restrict__ zc_g,
                                                short* __restrict__ SpT_g,
                                                float* __restrict__ zp_g,
                                                short* __restrict__ vT_g,
                                                float* __restrict__ out) {
    cg::grid_group grid = cg::this_grid();

    __shared__ __align__(16) union {
        struct {
            short KfT[DD][CHK + 8];    // [128][72] bf16  (KfT[d][t])
            short vT [CHK][CHK + 8];   // [64][72]  bf16  (vT[e_local][t])
            float SsT[CHK][DD + 4];    // [64][132] f32   (SsT[e_local][d])
        } a;                           // 61440 B
        struct {
            short Qf[CHK][DD + 8];     // [64][136]
            short Kf[CHK][DD + 8];
            short Ps[CHK][CHK + 8];    // [64][72]
            float zs[DD];
            float den[CHK];
        } c;                           // 44800 B
    } u;

    int bid = blockIdx.x, tid = threadIdx.x;
    int lane = tid & 63, w = tid >> 6, l15 = lane & 15, l4 = lane >> 4;
    const f32x4 z4 = {0.f, 0.f, 0.f, 0.f};

    int c = bid >> 1, h = bid & 1;
    const float* kc = kin + (size_t)c * CHK * DD;
    const float* vc = vin + (size_t)c * CHK * DD;

    // ================= phase 0 =================
    // W -> bf16, 16 float4s per block
    if (tid < 16) {
        int i = bid * 16 + tid;
        float4 v = *(const float4*)(W + (size_t)i * 4);
        unsigned lo = (unsigned short)f2b(v.x) | ((unsigned)(unsigned short)f2b(v.y) << 16);
        unsigned hi = (unsigned short)f2b(v.z) | ((unsigned)(unsigned short)f2b(v.w) << 16);
        uint2 p; p.x = lo; p.y = hi;
        *(uint2*)(Wb + i * 4) = p;
    }
    // vT half: v[t][64h + e_local], e_local 0..63 -> vT[e_local][t]
    #pragma unroll
    for (int it = 0; it < 4; ++it) {
        int i = tid + it * 256;               // 1024 float4s
        int t = i >> 4, c4 = (i & 15) * 4;
        float4 vv = *(const float4*)(vc + t * DD + 64 * h + c4);
        u.a.vT[c4 + 0][t] = f2b(vv.x); u.a.vT[c4 + 1][t] = f2b(vv.y);
        u.a.vT[c4 + 2][t] = f2b(vv.z); u.a.vT[c4 + 3][t] = f2b(vv.w);
    }
    // prefetch phi(k) A-fragments
    bf16x8 af[4];
    {
        int row = 16 * w + l15;
        #pragma unroll
        for (int kk = 0; kk < 4; ++kk)
            af[kk] = cvt8(kc + row * DD + kk * 32 + l4 * 8);
    }
    __threadfence();
    grid.sync();

    // ================= phase A =================
    // phi(k): wave w -> t rows 16w..16w+15, all e
    #pragma unroll
    for (int n = 0; n < 8; ++n) {
        int e = 16 * n + l15;
        f32x4 d = z4;
        #pragma unroll
        for (int kk = 0; kk < 4; ++kk) {
            bf16x8 bw = *(const bf16x8*)(Wb + e * DD + kk * 32 + l4 * 8);
            d = MFMA(af[kk], bw, d);
        }
        float bv = bias[e];
        #pragma unroll
        for (int j = 0; j < 4; ++j) {
            float zv = d[j] + bv;
            float r = (zv > 0.f) ? (zv + 1.f) : __expf(zv);   // ELU+1
            u.a.KfT[e][16 * w + l4 * 4 + j] = f2b(r);
        }
    }
    __syncthreads();

    // z_c (h==0 blocks)
    if (h == 0 && tid < DD) {
        float s = 0.f;
        #pragma unroll
        for (int t8 = 0; t8 < CHK / 8; ++t8) {
            bf16x8 kv = *(const bf16x8*)&u.a.KfT[tid][t8 * 8];
            #pragma unroll
            for (int j = 0; j < 8; ++j) s += b2f(kv[j]);
        }
        zc_g[(size_t)c * DD + tid] = s;
    }

    // store vT half -> global [c][e][t]
    #pragma unroll
    for (int it = 0; it < 2; ++it) {
        int i = tid + it * 256;               // 512 x bf16x8
        int e = i >> 3, t0 = (i & 7) * 8;
        *(bf16x8*)(vT_g + (size_t)c * DD * CHK + (64 * h + e) * CHK + t0) =
            *(const bf16x8*)&u.a.vT[e][t0];
    }

    // S-GEMM half: S[d][e_local] = sum_t KfT[d][t] * vT[e_local][t]
    {
        f32x4 sacc[2][4];
        #pragma unroll
        for (int mi = 0; mi < 2; ++mi)
            #pragma unroll
            for (int n = 0; n < 4; ++n) sacc[mi][n] = z4;
        #pragma unroll
        for (int kk = 0; kk < 2; ++kk) {
            bf16x8 afr[2];
            #pragma unroll
            for (int mi = 0; mi < 2; ++mi)
                afr[mi] = *(const bf16x8*)&u.a.KfT[16 * (2 * w + mi) + l15][kk * 32 + l4 * 8];
            #pragma unroll
            for (int n = 0; n < 4; ++n) {
                bf16x8 bfr = *(const bf16x8*)&u.a.vT[16 * n + l15][kk * 32 + l4 * 8];
                sacc[0][n] = MFMA(afr[0], bfr, sacc[0][n]);
                sacc[1][n] = MFMA(afr[1], bfr, sacc[1][n]);
            }
        }
        #pragma unroll
        for (int mi = 0; mi < 2; ++mi)
            #pragma unroll
            for (int n = 0; n < 4; ++n) {
                int e = 16 * n + l15;           // D col = e_local
                #pragma unroll
                for (int j = 0; j < 4; ++j)     // D row = d
                    u.a.SsT[e][16 * (2 * w + mi) + l4 * 4 + j] = sacc[mi][n][j];
            }
    }
    __syncthreads();

    // SsT half -> global fp32 [c][64h+e][d]
    {
        float* dst = SsT_g + (size_t)c * DD * DD + (size_t)64 * h * DD;
        #pragma unroll
        for (int it = 0; it < 8; ++it) {
            int i = tid + it * 256;           // 2048 float4s
            int e = i >> 5, c4 = (i & 31) * 4;
            *(float4*)(dst + e * DD + c4) = *(const float4*)&u.a.SsT[e][c4];
        }
    }
    __threadfence();
    grid.sync();

    // ================= phase B: exclusive scan over chunks =================
    {
        int t_id = bid * 2 + (tid >> 7);      // 0..511 = (b, e)
        int b = t_id >> 7, e = t_id & 127;
        int d = tid & 127;
        size_t base = ((size_t)(b * NCHK) * DD + e) * DD + d;
        const size_t stride = (size_t)DD * DD;

        float vals[NCHK];
        #pragma unroll
        for (int c2 = 0; c2 < NCHK; ++c2) vals[c2] = SsT_g[base + c2 * stride];
        float run = 0.f;
        #pragma unroll
        for (int c2 = 0; c2 < NCHK; ++c2) {
            SpT_g[base + c2 * stride] = f2b(run);
            run += vals[c2];
        }
        if (e == 0) {
            float vz[NCHK];
            #pragma unroll
            for (int c2 = 0; c2 < NCHK; ++c2) vz[c2] = zc_g[(size_t)(b * NCHK + c2) * DD + d];
            float rz = 0.f;
            #pragma unroll
            for (int c2 = 0; c2 < NCHK; ++c2) {
                zp_g[(size_t)(b * NCHK + c2) * DD + d] = rz;
                rz += vz[c2];
            }
        }
    }
    __threadfence();
    grid.sync();

    // ================= phase C: output =================
    if (tid < DD) u.c.zs[tid] = zp_g[(size_t)c * DD + tid];

    // phi(q), phi(k) full
    {
        const float* qc = q + (size_t)c * CHK * DD;
        bf16x8 afq[4], afk[4];
        int row = 16 * w + l15;
        #pragma unroll
        for (int kk = 0; kk < 4; ++kk) {
            afq[kk] = cvt8(qc + row * DD + kk * 32 + l4 * 8);
            afk[kk] = cvt8(kc + row * DD + kk * 32 + l4 * 8);
        }
        #pragma unroll
        for (int n = 0; n < 8; ++n) {
            int e = 16 * n + l15;
            f32x4 dq = z4, dk = z4;
            #pragma unroll
            for (int kk = 0; kk < 4; ++kk) {
                bf16x8 bw = *(const bf16x8*)(Wb + e * DD + kk * 32 + l4 * 8);
                dq = MFMA(afq[kk], bw, dq);
                dk = MFMA(afk[kk], bw, dk);
            }
            float bv = bias[e];
            #pragma unroll
            for (int j = 0; j < 4; ++j) {
                int t = 16 * w + l4 * 4 + j;
                float zq = dq[j] + bv;
                u.c.Qf[t][e] = f2b((zq > 0.f) ? (zq + 1.f) : __expf(zq));
                float zk = dk[j] + bv;
                u.c.Kf[t][e] = f2b((zk > 0.f) ? (zk + 1.f) : __expf(zk));
            }
        }
    }
    __syncthreads();

    // QK^T causal -> Ps
    bf16x8 aq[4];
    #pragma unroll
    for (int kk = 0; kk < 4; ++kk)
        aq[kk] = *(const bf16x8*)&u.c.Qf[16 * w + l15][kk * 32 + l4 * 8];
    #pragma unroll
    for (int n2 = 0; n2 < 4; ++n2) {
        f32x4 p = z4;
        #pragma unroll
        for (int kk = 0; kk < 4; ++kk) {
            bf16x8 bk = *(const bf16x8*)&u.c.Kf[16 * n2 + l15][kk * 32 + l4 * 8];
            p = MFMA(aq[kk], bk, p);
        }
        int t2 = 16 * n2 + l15;
        #pragma unroll
        for (int j = 0; j < 4; ++j) {
            int t = 16 * w + l4 * 4 + j;
            u.c.Ps[t][t2] = (t2 <= t) ? f2b(p[j]) : (short)0;
        }
    }
    __syncthreads();

    // den (wave 0, redundant per half-block)
    if (tid < CHK) {
        float s = 1e-6f;
        #pragma unroll
        for (int t8 = 0; t8 < CHK / 8; ++t8) {
            bf16x8 pv = *(const bf16x8*)&u.c.Ps[tid][t8 * 8];
            #pragma unroll
            for (int j = 0; j < 8; ++j) s += b2f(pv[j]);
        }
        #pragma unroll
        for (int d8 = 0; d8 < DD / 8; ++d8) {
            bf16x8 qv = *(const bf16x8*)&u.c.Qf[tid][d8 * 8];
            #pragma unroll
            for (int j = 0; j < 8; ++j) s += b2f(qv[j]) * u.c.zs[d8 * 8 + j];
        }
        u.c.den[tid] = s;
    }

    // out half: n = 0..3, e = 64h + 16n + l15
    bf16x8 ap[2];
    #pragma unroll
    for (int kk = 0; kk < 2; ++kk)
        ap[kk] = *(const bf16x8*)&u.c.Ps[16 * w + l15][kk * 32 + l4 * 8];

    const short* Sp  = SpT_g + (size_t)c * DD * DD;
    const short* vTg = vT_g + (size_t)c * DD * CHK;
    f32x4 oacc[4];
    #pragma unroll
    for (int n = 0; n < 4; ++n) oacc[n] = z4;
    #pragma unroll
    for (int n = 0; n < 4; ++n) {
        int e = 64 * h + 16 * n + l15;
        #pragma unroll
        for (int kk = 0; kk < 4; ++kk) {
            bf16x8 bs = *(const bf16x8*)(Sp + e * DD + kk * 32 + l4 * 8);
            oacc[n] = MFMA(aq[kk], bs, oacc[n]);
        }
        #pragma unroll
        for (int kk = 0; kk < 2; ++kk) {
            bf16x8 bv = *(const bf16x8*)(vTg + e * CHK + kk * 32 + l4 * 8);
            oacc[n] = MFMA(ap[kk], bv, oacc[n]);
        }
    }
    __syncthreads();   // den ready

    float* oc = out + (size_t)c * CHK * DD;
    float invs[4];
    #pragma unroll
    for (int j = 0; j < 4; ++j) invs[j] = 1.0f / u.c.den[16 * w + l4 * 4 + j];
    #pragma unroll
    for (int n = 0; n < 4; ++n) {
        int e = 64 * h + 16 * n + l15;
        #pragma unroll
        for (int j = 0; j < 4; ++j) {
            int t = 16 * w + l4 * 4 + j;
            oc[t * DD + e] = oacc[n][j] * invs[j];
        }
    }
}

// ---------------------------------------------------------------------------
extern "C" void kernel_launch(void* const* d_in, const int* in_sizes, int n_in,
                              void* d_out, int out_size, void* d_ws, size_t ws_size,
                              hipStream_t stream) {
    const float* q  = (const float*)d_in[0];
    const float* k  = (const float*)d_in[1];
    const float* v  = (const float*)d_in[2];
    const float* W  = (const float*)d_in[3];
    const float* bi = (const float*)d_in[4];
    float* out = (float*)d_out;

    float* SsT_g = (float*)d_ws;                        // 128*128*128 f32 = 8 MB
    float* zc_g  = SsT_g + (size_t)NCHKS * DD * DD;     // 16384 f32
    float* zp_g  = zc_g + (size_t)NCHKS * DD;           // 16384 f32
    short* Wb    = (short*)(zp_g + (size_t)NCHKS * DD); // 16384 bf16
    short* SpT_g = Wb + DD * DD;                        // 4 MB bf16
    short* vT_g  = SpT_g + (size_t)NCHKS * DD * DD;     // 2 MB bf16

    void* kargs[] = {
        (void*)&q, (void*)&k, (void*)&v, (void*)&W, (void*)&bi,
        (void*)&Wb, (void*)&SsT_g, (void*)&zc_g, (void*)&SpT_g,
        (void*)&zp_g, (void*)&vT_g, (void*)&out
    };
    hipLaunchCooperativeKernel((void*)fused, dim3(NBLK), dim3(256), kargs, 0, stream);
}

// Round 4
// 29.165 us; speedup vs baseline: 7.3466x; 7.3466x over previous
//
#include <hip/hip_runtime.h>
#include <hip/hip_bf16.h>

#define BB 4
#define TT 2048
#define DD 128
#define CHK 64
#define NCHK 32            // TT/CHK
#define NCHKS (BB*NCHK)    // 128 chunks total

typedef __attribute__((ext_vector_type(8))) short  bf16x8;
typedef __attribute__((ext_vector_type(4))) float  f32x4;

#define MFMA(a,b,c) __builtin_amdgcn_mfma_f32_16x16x32_bf16(a, b, c, 0, 0, 0)

__device__ __forceinline__ short f2b(float f) {
    union { float f; unsigned u; } x; x.f = f;
    unsigned r = x.u + 0x7fffu + ((x.u >> 16) & 1u);   // RNE
    return (short)(r >> 16);
}
__device__ __forceinline__ float b2f(short s) {
    union { unsigned u; float f; } x; x.u = ((unsigned)(unsigned short)s) << 16;
    return x.f;
}
__device__ __forceinline__ bf16x8 cvt8(const float* p) {
    float4 a = *(const float4*)p, b = *(const float4*)(p + 4);
    bf16x8 r;
    r[0]=f2b(a.x); r[1]=f2b(a.y); r[2]=f2b(a.z); r[3]=f2b(a.w);
    r[4]=f2b(b.x); r[5]=f2b(b.y); r[6]=f2b(b.z); r[7]=f2b(b.w);
    return r;
}

// W fp32 [128][128] -> LDS bf16 [128][136] (padded: 272B stride -> conflict-free frags)
__device__ __forceinline__ void w_to_lds(const float* __restrict__ W,
                                         short (*Wl)[DD + 8], int tid) {
    #pragma unroll
    for (int it = 0; it < 16; ++it) {
        int i = tid + it * 256;               // 4096 float4s
        int row = i >> 5, c4 = (i & 31) * 4;
        float4 v = *(const float4*)(W + (size_t)row * DD + c4);
        unsigned lo = (unsigned short)f2b(v.x) | ((unsigned)(unsigned short)f2b(v.y) << 16);
        unsigned hi = (unsigned short)f2b(v.z) | ((unsigned)(unsigned short)f2b(v.w) << 16);
        uint2 p; p.x = lo; p.y = hi;
        *(uint2*)&Wl[row][c4] = p;
    }
}

// ---------------------------------------------------------------------------
// K1: block (c, h): phi(k_c) (full), z_c (h==0), vT half -> global,
//     S_half[d][e_local] = Kf^T V_half -> SsT_g fp32 [c][e][d].
// grid 256 blocks x 256 thr.
// ---------------------------------------------------------------------------
__global__ __launch_bounds__(256) void k1_chunk(const float* __restrict__ kin,
                                                const float* __restrict__ vin,
                                                const float* __restrict__ W,
                                                const float* __restrict__ bias,
                                                float* __restrict__ SsT_g,
                                                float* __restrict__ zc_g,
                                                short* __restrict__ vT_g) {
    int c = blockIdx.x >> 1, h = blockIdx.x & 1;
    const float* kc = kin + (size_t)c * CHK * DD;
    const float* vc = vin + (size_t)c * CHK * DD;

    __shared__ __align__(16) short Wl [DD][DD + 8];    // 34.8 KB
    __shared__ __align__(16) short KfT[DD][CHK + 8];   // 18 KB   (KfT[d][t])
    __shared__ __align__(16) short vT [CHK][CHK + 8];  // 9 KB    (vT[e_local][t])
    __shared__ __align__(16) float SsT[CHK][DD + 4];   // 33.8 KB (SsT[e_local][d])

    int tid = threadIdx.x, lane = tid & 63, w = tid >> 6;
    int l15 = lane & 15, l4 = lane >> 4;
    const f32x4 z4 = {0.f, 0.f, 0.f, 0.f};

    // prefetch phi(k) A-fragments from global (independent of LDS)
    bf16x8 af[4];
    {
        int row = 16 * w + l15;
        #pragma unroll
        for (int kk = 0; kk < 4; ++kk)
            af[kk] = cvt8(kc + row * DD + kk * 32 + l4 * 8);
    }
    w_to_lds(W, Wl, tid);
    // vT half: v[t][64h + e_local] -> vT[e_local][t]
    #pragma unroll
    for (int it = 0; it < 4; ++it) {
        int i = tid + it * 256;               // 1024 float4s
        int t = i >> 4, c4 = (i & 15) * 4;
        float4 vv = *(const float4*)(vc + t * DD + 64 * h + c4);
        vT[c4 + 0][t] = f2b(vv.x); vT[c4 + 1][t] = f2b(vv.y);
        vT[c4 + 2][t] = f2b(vv.z); vT[c4 + 3][t] = f2b(vv.w);
    }
    __syncthreads();

    // phi(k): wave w -> t rows 16w..16w+15, all e
    #pragma unroll
    for (int n = 0; n < 8; ++n) {
        int e = 16 * n + l15;
        f32x4 d = z4;
        #pragma unroll
        for (int kk = 0; kk < 4; ++kk) {
            bf16x8 bw = *(const bf16x8*)&Wl[e][kk * 32 + l4 * 8];
            d = MFMA(af[kk], bw, d);
        }
        float bv = bias[e];
        #pragma unroll
        for (int j = 0; j < 4; ++j) {
            float zv = d[j] + bv;
            float r = (zv > 0.f) ? (zv + 1.f) : __expf(zv);   // ELU+1
            KfT[e][16 * w + l4 * 4 + j] = f2b(r);
        }
    }
    __syncthreads();

    // z_c (h==0 blocks)
    if (h == 0 && tid < DD) {
        float s = 0.f;
        #pragma unroll
        for (int t8 = 0; t8 < CHK / 8; ++t8) {
            bf16x8 kv = *(const bf16x8*)&KfT[tid][t8 * 8];
            #pragma unroll
            for (int j = 0; j < 8; ++j) s += b2f(kv[j]);
        }
        zc_g[(size_t)c * DD + tid] = s;
    }

    // store vT half -> global [c][e][t]
    #pragma unroll
    for (int it = 0; it < 2; ++it) {
        int i = tid + it * 256;               // 512 x bf16x8
        int e = i >> 3, t0 = (i & 7) * 8;
        *(bf16x8*)(vT_g + (size_t)c * DD * CHK + (64 * h + e) * CHK + t0) =
            *(const bf16x8*)&vT[e][t0];
    }

    // S-GEMM half: S[d][e_local] = sum_t KfT[d][t] * vT[e_local][t]
    {
        f32x4 sacc[2][4];
        #pragma unroll
        for (int mi = 0; mi < 2; ++mi)
            #pragma unroll
            for (int n = 0; n < 4; ++n) sacc[mi][n] = z4;
        #pragma unroll
        for (int kk = 0; kk < 2; ++kk) {
            bf16x8 afr[2];
            #pragma unroll
            for (int mi = 0; mi < 2; ++mi)
                afr[mi] = *(const bf16x8*)&KfT[16 * (2 * w + mi) + l15][kk * 32 + l4 * 8];
            #pragma unroll
            for (int n = 0; n < 4; ++n) {
                bf16x8 bfr = *(const bf16x8*)&vT[16 * n + l15][kk * 32 + l4 * 8];
                sacc[0][n] = MFMA(afr[0], bfr, sacc[0][n]);
                sacc[1][n] = MFMA(afr[1], bfr, sacc[1][n]);
            }
        }
        #pragma unroll
        for (int mi = 0; mi < 2; ++mi)
            #pragma unroll
            for (int n = 0; n < 4; ++n) {
                int e = 16 * n + l15;           // D col = e_local
                #pragma unroll
                for (int j = 0; j < 4; ++j)     // D row = d
                    SsT[e][16 * (2 * w + mi) + l4 * 4 + j] = sacc[mi][n][j];
            }
    }
    __syncthreads();

    // SsT half -> global fp32 [c][64h+e][d]
    float* dst = SsT_g + (size_t)c * DD * DD + (size_t)64 * h * DD;
    #pragma unroll
    for (int it = 0; it < 8; ++it) {
        int i = tid + it * 256;               // 2048 float4s
        int e = i >> 5, c4 = (i & 31) * 4;
        *(float4*)(dst + e * DD + c4) = *(const float4*)&SsT[e][c4];
    }
}

// ---------------------------------------------------------------------------
// K2: exclusive prefix over chunks. grid 512 = (b,e) x 128 thr (thread = d).
// ---------------------------------------------------------------------------
__global__ __launch_bounds__(128) void k2_scan(const float* __restrict__ SsT_g,
                                               const float* __restrict__ zc_g,
                                               short* __restrict__ SpT_g,
                                               float* __restrict__ zp_g) {
    int e = blockIdx.x & 127, b = blockIdx.x >> 7;
    int d = threadIdx.x;
    size_t base = ((size_t)(b * NCHK) * DD + e) * DD + d;
    const size_t stride = (size_t)DD * DD;

    float vals[NCHK];
    #pragma unroll
    for (int c2 = 0; c2 < NCHK; ++c2) vals[c2] = SsT_g[base + c2 * stride];
    float run = 0.f;
    #pragma unroll
    for (int c2 = 0; c2 < NCHK; ++c2) {
        SpT_g[base + c2 * stride] = f2b(run);
        run += vals[c2];
    }
    if (e == 0) {
        float vz[NCHK];
        #pragma unroll
        for (int c2 = 0; c2 < NCHK; ++c2) vz[c2] = zc_g[(size_t)(b * NCHK + c2) * DD + d];
        float rz = 0.f;
        #pragma unroll
        for (int c2 = 0; c2 < NCHK; ++c2) {
            zp_g[(size_t)(b * NCHK + c2) * DD + d] = rz;
            rz += vz[c2];
        }
    }
}

// ---------------------------------------------------------------------------
// K3: block (c, h): phi(q),phi(k) full; P=QK^T causal -> Ps bf16; den;
//     out half = Ps@V + Q@Sp; divide; store fp32.
// grid 256 blocks x 256 thr.
// ---------------------------------------------------------------------------
__global__ __launch_bounds__(256) void k3_out(const float* __restrict__ q,
                                              const float* __restrict__ kin,
                                              const float* __restrict__ W,
                                              const float* __restrict__ bias,
                                              const short* __restrict__ SpT_g,
                                              const float* __restrict__ zp_g,
                                              const short* __restrict__ vT_g,
                                              float* __restrict__ out) {
    int c = blockIdx.x >> 1, h = blockIdx.x & 1;

    __shared__ __align__(16) short Wl[DD][DD + 8];     // 34.8 KB
    __shared__ __align__(16) short Qf[CHK][DD + 8];    // 17.4 KB
    __shared__ __align__(16) short Kf[CHK][DD + 8];    // 17.4 KB
    __shared__ __align__(16) short Ps[CHK][CHK + 8];   // 9.2 KB
    __shared__ float zs[DD];
    __shared__ float den[CHK];

    int tid = threadIdx.x, lane = tid & 63, w = tid >> 6;
    int l15 = lane & 15, l4 = lane >> 4;
    const f32x4 z4 = {0.f, 0.f, 0.f, 0.f};

    if (tid < DD) zs[tid] = zp_g[(size_t)c * DD + tid];

    // prefetch A-frags for phi(q), phi(k)
    const float* qc = q   + (size_t)c * CHK * DD;
    const float* kc = kin + (size_t)c * CHK * DD;
    bf16x8 afq[4], afk[4];
    {
        int row = 16 * w + l15;
        #pragma unroll
        for (int kk = 0; kk < 4; ++kk) {
            afq[kk] = cvt8(qc + row * DD + kk * 32 + l4 * 8);
            afk[kk] = cvt8(kc + row * DD + kk * 32 + l4 * 8);
        }
    }
    w_to_lds(W, Wl, tid);
    __syncthreads();

    // phi(q), phi(k): wave w -> rows 16w..16w+15
    #pragma unroll
    for (int n = 0; n < 8; ++n) {
        int e = 16 * n + l15;
        f32x4 dq = z4, dk = z4;
        #pragma unroll
        for (int kk = 0; kk < 4; ++kk) {
            bf16x8 bw = *(const bf16x8*)&Wl[e][kk * 32 + l4 * 8];
            dq = MFMA(afq[kk], bw, dq);
            dk = MFMA(afk[kk], bw, dk);
        }
        float bv = bias[e];
        #pragma unroll
        for (int j = 0; j < 4; ++j) {
            int t = 16 * w + l4 * 4 + j;
            float zq = dq[j] + bv;
            Qf[t][e] = f2b((zq > 0.f) ? (zq + 1.f) : __expf(zq));
            float zk = dk[j] + bv;
            Kf[t][e] = f2b((zk > 0.f) ? (zk + 1.f) : __expf(zk));
        }
    }
    __syncthreads();

    // QK^T causal -> Ps
    bf16x8 aq[4];
    #pragma unroll
    for (int kk = 0; kk < 4; ++kk)
        aq[kk] = *(const bf16x8*)&Qf[16 * w + l15][kk * 32 + l4 * 8];
    #pragma unroll
    for (int n2 = 0; n2 < 4; ++n2) {
        f32x4 p = z4;
        #pragma unroll
        for (int kk = 0; kk < 4; ++kk) {
            bf16x8 bk = *(const bf16x8*)&Kf[16 * n2 + l15][kk * 32 + l4 * 8];
            p = MFMA(aq[kk], bk, p);
        }
        int t2 = 16 * n2 + l15;
        #pragma unroll
        for (int j = 0; j < 4; ++j) {
            int t = 16 * w + l4 * 4 + j;
            Ps[t][t2] = (t2 <= t) ? f2b(p[j]) : (short)0;
        }
    }
    __syncthreads();

    // den (wave 0, redundant per half-block)
    if (tid < CHK) {
        float s = 1e-6f;
        #pragma unroll
        for (int t8 = 0; t8 < CHK / 8; ++t8) {
            bf16x8 pv = *(const bf16x8*)&Ps[tid][t8 * 8];
            #pragma unroll
            for (int j = 0; j < 8; ++j) s += b2f(pv[j]);
        }
        #pragma unroll
        for (int d8 = 0; d8 < DD / 8; ++d8) {
            bf16x8 qv = *(const bf16x8*)&Qf[tid][d8 * 8];
            #pragma unroll
            for (int j = 0; j < 8; ++j) s += b2f(qv[j]) * zs[d8 * 8 + j];
        }
        den[tid] = s;
    }

    // out half: e = 64h + 16n + l15, n = 0..3
    bf16x8 ap[2];
    #pragma unroll
    for (int kk = 0; kk < 2; ++kk)
        ap[kk] = *(const bf16x8*)&Ps[16 * w + l15][kk * 32 + l4 * 8];

    const short* Sp  = SpT_g + (size_t)c * DD * DD;
    const short* vTg = vT_g + (size_t)c * DD * CHK;
    f32x4 oacc[4];
    #pragma unroll
    for (int n = 0; n < 4; ++n) oacc[n] = z4;
    #pragma unroll
    for (int n = 0; n < 4; ++n) {
        int e = 64 * h + 16 * n + l15;
        #pragma unroll
        for (int kk = 0; kk < 4; ++kk) {
            bf16x8 bs = *(const bf16x8*)(Sp + e * DD + kk * 32 + l4 * 8);
            oacc[n] = MFMA(aq[kk], bs, oacc[n]);
        }
        #pragma unroll
        for (int kk = 0; kk < 2; ++kk) {
            bf16x8 bv = *(const bf16x8*)(vTg + e * CHK + kk * 32 + l4 * 8);
            oacc[n] = MFMA(ap[kk], bv, oacc[n]);
        }
    }
    __syncthreads();   // den ready

    float* oc = out + (size_t)c * CHK * DD;
    float invs[4];
    #pragma unroll
    for (int j = 0; j < 4; ++j) invs[j] = 1.0f / den[16 * w + l4 * 4 + j];
    #pragma unroll
    for (int n = 0; n < 4; ++n) {
        int e = 64 * h + 16 * n + l15;
        #pragma unroll
        for (int j = 0; j < 4; ++j) {
            int t = 16 * w + l4 * 4 + j;
            oc[t * DD + e] = oacc[n][j] * invs[j];
        }
    }
}

// ---------------------------------------------------------------------------
extern "C" void kernel_launch(void* const* d_in, const int* in_sizes, int n_in,
                              void* d_out, int out_size, void* d_ws, size_t ws_size,
                              hipStream_t stream) {
    const float* q  = (const float*)d_in[0];
    const float* k  = (const float*)d_in[1];
    const float* v  = (const float*)d_in[2];
    const float* W  = (const float*)d_in[3];
    const float* bi = (const float*)d_in[4];
    float* out = (float*)d_out;

    float* SsT_g = (float*)d_ws;                        // 128*128*128 f32 = 8 MB
    float* zc_g  = SsT_g + (size_t)NCHKS * DD * DD;     // 16384 f32
    float* zp_g  = zc_g + (size_t)NCHKS * DD;           // 16384 f32
    short* SpT_g = (short*)(zp_g + (size_t)NCHKS * DD); // 4 MB bf16
    short* vT_g  = SpT_g + (size_t)NCHKS * DD * DD;     // 2 MB bf16

    k1_chunk<<<2 * NCHKS, 256, 0, stream>>>(k, v, W, bi, SsT_g, zc_g, vT_g);
    k2_scan<<<512, 128, 0, stream>>>(SsT_g, zc_g, SpT_g, zp_g);
    k3_out<<<2 * NCHKS, 256, 0, stream>>>(q, k, W, bi, SpT_g, zp_g, vT_g, out);
}